// Round 1
// baseline (200.742 us; speedup 1.0000x reference)
//
#include <hip/hip_runtime.h>
#include <stdint.h>

#define B_SZ 2
#define T_SZ 2048
#define DMODEL 1024
#define HCNT 16
#define HD 64
#define MROWS (B_SZ * T_SZ)  // 4096

typedef __attribute__((ext_vector_type(8))) __bf16 bf16x8;
typedef __attribute__((ext_vector_type(4))) float f32x4;
typedef __attribute__((ext_vector_type(8))) unsigned short u16x8;

__device__ __forceinline__ unsigned short f2bf(float f) {
  union { float f; uint32_t u; } v; v.f = f;
  uint32_t u = v.u;
  u += 0x7fffu + ((u >> 16) & 1u);
  return (unsigned short)(u >> 16);
}

__device__ __forceinline__ void gld_lds16(const void* g, void* l) {
  __builtin_amdgcn_global_load_lds((__attribute__((address_space(1))) void*)(uintptr_t)g,
                                   (__attribute__((address_space(3))) void*)l, 16, 0, 0);
}

// ---------------- fp32 -> bf16 convert ----------------
__global__ __launch_bounds__(256)
void cvt_bf16(const float* __restrict__ in, unsigned short* __restrict__ out, int n4) {
  int i = blockIdx.x * 256 + threadIdx.x;
  if (i >= n4) return;
  float4 v = ((const float4*)in)[i];
  ushort4 o;
  o.x = f2bf(v.x); o.y = f2bf(v.y); o.z = f2bf(v.z); o.w = f2bf(v.w);
  ((ushort4*)out)[i] = o;
}

// ---------------- RMSNorm (fp32 in, bf16 out) ----------------
__global__ __launch_bounds__(256)
void rmsnorm_bf16(const float* __restrict__ x, const float* __restrict__ w,
                  unsigned short* __restrict__ xn) {
  const int row = blockIdx.x;
  const int t = threadIdx.x;
  float4 v = ((const float4*)(x + (size_t)row * DMODEL))[t];
  float ss = v.x * v.x + v.y * v.y + v.z * v.z + v.w * v.w;
#pragma unroll
  for (int o = 1; o < 64; o <<= 1) ss += __shfl_xor(ss, o, 64);
  __shared__ float red[4];
  if ((t & 63) == 0) red[t >> 6] = ss;
  __syncthreads();
  float tot = red[0] + red[1] + red[2] + red[3];
  float scale = rsqrtf(tot * (1.0f / (float)DMODEL) + 1e-6f);
  float4 wv = ((const float4*)w)[t];
  ushort4 o;
  o.x = f2bf(v.x * scale * wv.x);
  o.y = f2bf(v.y * scale * wv.y);
  o.z = f2bf(v.z * scale * wv.z);
  o.w = f2bf(v.w * scale * wv.w);
  ((ushort4*)(xn + (size_t)row * DMODEL))[t] = o;
}

// ---------------- bf16 NT GEMM: C[M][N] = A[M][K] * B[N][K]^T ----------------
// 128x128 tile, BK=32, 4 waves (each 64x64), m97 structure.
__device__ __forceinline__ void stage128x32(const unsigned short* g, int ldg,
                                            unsigned short* lds, int wave, int lane) {
#pragma unroll
  for (int i = 0; i < 2; ++i) {
    const unsigned short* gp = g + (size_t)(i * 64 + wave * 16 + (lane >> 2)) * ldg + (lane & 3) * 8;
    gld_lds16(gp, lds + i * 2048 + wave * 512);  // wave-uniform LDS base; HW adds lane*16B
  }
}

template <int F32OUT>
__global__ __launch_bounds__(256, 2)
void gemm_bt(const unsigned short* __restrict__ A, const unsigned short* __restrict__ B,
             void* __restrict__ Cv, int M, int N, int K) {
  __shared__ __align__(16) unsigned short As[2][128 * 32];
  __shared__ __align__(16) unsigned short Bs[2][128 * 32];
  const int t = threadIdx.x, wave = t >> 6, lane = t & 63;
  const int m0 = blockIdx.y * 128, n0 = blockIdx.x * 128;
  const int wr = wave >> 1, wc = wave & 1;
  f32x4 acc[4][4] = {};
  const int nk = K >> 5;
  stage128x32(A + (size_t)m0 * K, K, As[0], wave, lane);
  stage128x32(B + (size_t)n0 * K, K, Bs[0], wave, lane);
  __syncthreads();
  int buf = 0;
  for (int kt = 0; kt < nk; ++kt) {
    if (kt + 1 < nk) {
      stage128x32(A + (size_t)m0 * K + (kt + 1) * 32, K, As[buf ^ 1], wave, lane);
      stage128x32(B + (size_t)n0 * K + (kt + 1) * 32, K, Bs[buf ^ 1], wave, lane);
    }
    bf16x8 af[4], bfr[4];
#pragma unroll
    for (int mi = 0; mi < 4; ++mi)
      af[mi] = *(const bf16x8*)&As[buf][(wr * 64 + mi * 16 + (lane & 15)) * 32 + (lane >> 4) * 8];
#pragma unroll
    for (int ni = 0; ni < 4; ++ni)
      bfr[ni] = *(const bf16x8*)&Bs[buf][(wc * 64 + ni * 16 + (lane & 15)) * 32 + (lane >> 4) * 8];
#pragma unroll
    for (int mi = 0; mi < 4; ++mi)
#pragma unroll
      for (int ni = 0; ni < 4; ++ni)
        acc[mi][ni] = __builtin_amdgcn_mfma_f32_16x16x32_bf16(af[mi], bfr[ni], acc[mi][ni], 0, 0, 0);
    __syncthreads();
    buf ^= 1;
  }
  const int cr = (lane >> 4) * 4, cc = lane & 15;
#pragma unroll
  for (int mi = 0; mi < 4; ++mi)
#pragma unroll
    for (int ni = 0; ni < 4; ++ni) {
      int row = m0 + wr * 64 + mi * 16 + cr;
      int col = n0 + wc * 64 + ni * 16 + cc;
      if (F32OUT) {
        float* C = (float*)Cv;
#pragma unroll
        for (int r = 0; r < 4; ++r) C[(size_t)(row + r) * N + col] = acc[mi][ni][r];
      } else {
        unsigned short* C = (unsigned short*)Cv;
#pragma unroll
        for (int r = 0; r < 4; ++r) C[(size_t)(row + r) * N + col] = f2bf(acc[mi][ni][r]);
      }
    }
}

// ---------------- causal flash attention ----------------
// grid: (T/128, B*H). 4 waves/block, each wave owns 32 q-rows. KVBLK=64.
__global__ __launch_bounds__(256, 2)
void attn_causal(const unsigned short* __restrict__ qkv, unsigned short* __restrict__ ctx) {
  __shared__ __align__(16) unsigned short Ks[64 * 64];
  __shared__ __align__(16) unsigned short Vt[64 * 64];
  __shared__ __align__(16) unsigned short Pl[4][32 * 72];
  const int t = threadIdx.x, wave = t >> 6, lane = t & 63;
  const int qt = blockIdx.x;
  const int bh = blockIdx.y;
  const int b = bh >> 4, h = bh & 15;
  const size_t base = (size_t)b * T_SZ * 3 * DMODEL;
  const int koffK = DMODEL + h * HD;
  const int koffV = 2 * DMODEL + h * HD;
  const int q0w = qt * 128 + wave * 32;

  // hoist Q fragments (rows q0w..q0w+31, all of d=64)
  bf16x8 aq[2][2];
#pragma unroll
  for (int mi = 0; mi < 2; ++mi)
#pragma unroll
    for (int kk = 0; kk < 2; ++kk) {
      int q = q0w + mi * 16 + (lane & 15);
      aq[mi][kk] = *(const bf16x8*)(qkv + base + (size_t)q * 3 * DMODEL + h * HD + kk * 32 + (lane >> 4) * 8);
    }

  float mst[2][4], lst[2][4];
  f32x4 aco[2][4];
#pragma unroll
  for (int mi = 0; mi < 2; ++mi)
#pragma unroll
    for (int r = 0; r < 4; ++r) { mst[mi][r] = -3e38f; lst[mi][r] = 0.f; }
#pragma unroll
  for (int mi = 0; mi < 2; ++mi)
#pragma unroll
    for (int ni = 0; ni < 4; ++ni)
#pragma unroll
      for (int r = 0; r < 4; ++r) aco[mi][ni][r] = 0.f;

  const int kend = qt * 128 + 128;
  for (int kb = 0; kb < kend; kb += 64) {
    if (kb) __syncthreads();
    // stage K tile [64][64] via global_load_lds; source pre-swizzled (chunk ^= row&7)
#pragma unroll
    for (int i = 0; i < 2; ++i) {
      int kr = i * 32 + wave * 8 + (lane >> 3);
      int c = lane & 7;
      const unsigned short* gp = qkv + base + (size_t)(kb + kr) * 3 * DMODEL + koffK + ((c ^ (kr & 7)) * 8);
      gld_lds16(gp, Ks + i * 2048 + wave * 512);
    }
    // stage V transposed: Vt[dd][k], swizzled (chunk ^= dd&7)
    {
      int kv = t >> 2, dd0 = (t & 3) * 16;
      const unsigned short* gp = qkv + base + (size_t)(kb + kv) * 3 * DMODEL + koffV + dd0;
      u16x8 v0 = *(const u16x8*)gp;
      u16x8 v1 = *(const u16x8*)(gp + 8);
#pragma unroll
      for (int j = 0; j < 8; ++j) {
        int dd = dd0 + j;
        Vt[dd * 64 + (((kv >> 3) ^ (dd & 7)) * 8) + (kv & 7)] = v0[j];
        dd = dd0 + 8 + j;
        Vt[dd * 64 + (((kv >> 3) ^ (dd & 7)) * 8) + (kv & 7)] = v1[j];
      }
    }
    __syncthreads();
    if (kb > q0w + 31) continue;  // wave fully above diagonal: skip compute, keep barriers

    // S = Q K^T  (32x64, K=64)
    f32x4 s[2][4] = {};
#pragma unroll
    for (int kk = 0; kk < 2; ++kk) {
      bf16x8 bk[4];
#pragma unroll
      for (int ni = 0; ni < 4; ++ni) {
        int row = ni * 16 + (lane & 15);
        int crd = kk * 4 + (lane >> 4);
        bk[ni] = *(const bf16x8*)&Ks[row * 64 + ((crd ^ (row & 7)) * 8)];
      }
#pragma unroll
      for (int mi = 0; mi < 2; ++mi)
#pragma unroll
        for (int ni = 0; ni < 4; ++ni)
          s[mi][ni] = __builtin_amdgcn_mfma_f32_16x16x32_bf16(aq[mi][kk], bk[ni], s[mi][ni], 0, 0, 0);
    }
    const bool domask = (kb + 63 > q0w);
#pragma unroll
    for (int mi = 0; mi < 2; ++mi)
#pragma unroll
      for (int ni = 0; ni < 4; ++ni)
#pragma unroll
        for (int r = 0; r < 4; ++r) {
          float v = s[mi][ni][r] * 0.125f;
          if (domask) {
            int gq = q0w + mi * 16 + (lane >> 4) * 4 + r;
            int gk = kb + ni * 16 + (lane & 15);
            if (gk > gq) v = -1e30f;
          }
          s[mi][ni][r] = v;
        }
    // online softmax (row r_s = mi*16 + (lane>>4)*4 + reg; cols across ni and lane&15)
#pragma unroll
    for (int mi = 0; mi < 2; ++mi)
#pragma unroll
      for (int r = 0; r < 4; ++r) {
        float rm = fmaxf(fmaxf(s[mi][0][r], s[mi][1][r]), fmaxf(s[mi][2][r], s[mi][3][r]));
        rm = fmaxf(rm, __shfl_xor(rm, 1, 16));
        rm = fmaxf(rm, __shfl_xor(rm, 2, 16));
        rm = fmaxf(rm, __shfl_xor(rm, 4, 16));
        rm = fmaxf(rm, __shfl_xor(rm, 8, 16));
        float mo = mst[mi][r];
        float mn = fmaxf(mo, rm);
        float corr = __expf(mo - mn);
        float rs = 0.f;
#pragma unroll
        for (int ni = 0; ni < 4; ++ni) {
          float p = __expf(s[mi][ni][r] - mn);
          s[mi][ni][r] = p;
          rs += p;
        }
        rs += __shfl_xor(rs, 1, 16);
        rs += __shfl_xor(rs, 2, 16);
        rs += __shfl_xor(rs, 4, 16);
        rs += __shfl_xor(rs, 8, 16);
        lst[mi][r] = lst[mi][r] * corr + rs;
        mst[mi][r] = mn;
#pragma unroll
        for (int ni = 0; ni < 4; ++ni) aco[mi][ni][r] *= corr;
      }
    // write P (bf16) to per-wave LDS, padded stride 72
    {
      unsigned short* P = Pl[wave];
#pragma unroll
      for (int mi = 0; mi < 2; ++mi)
#pragma unroll
        for (int ni = 0; ni < 4; ++ni)
#pragma unroll
          for (int r = 0; r < 4; ++r) {
            int row = mi * 16 + (lane >> 4) * 4 + r;
            int col = ni * 16 + (lane & 15);
            P[row * 72 + col] = f2bf(s[mi][ni][r]);
          }
      // PV: O += P[32x64] * V[64x64]
#pragma unroll
      for (int kk = 0; kk < 2; ++kk) {
        bf16x8 pa[2], bv[4];
#pragma unroll
        for (int mi = 0; mi < 2; ++mi)
          pa[mi] = *(const bf16x8*)&P[(mi * 16 + (lane & 15)) * 72 + kk * 32 + (lane >> 4) * 8];
#pragma unroll
        for (int ni = 0; ni < 4; ++ni) {
          int dd = ni * 16 + (lane & 15);
          int crd = kk * 4 + (lane >> 4);
          bv[ni] = *(const bf16x8*)&Vt[dd * 64 + ((crd ^ (dd & 7)) * 8)];
        }
#pragma unroll
        for (int mi = 0; mi < 2; ++mi)
#pragma unroll
          for (int ni = 0; ni < 4; ++ni)
            aco[mi][ni] = __builtin_amdgcn_mfma_f32_16x16x32_bf16(pa[mi], bv[ni], aco[mi][ni], 0, 0, 0);
      }
    }
  }
  // epilogue: O /= l, store ctx[b][q][h*64+dd] bf16
  unsigned short* outp = ctx + (size_t)b * T_SZ * DMODEL + h * HD;
#pragma unroll
  for (int mi = 0; mi < 2; ++mi)
#pragma unroll
    for (int r = 0; r < 4; ++r) {
      int q = q0w + mi * 16 + (lane >> 4) * 4 + r;
      float inv = 1.f / lst[mi][r];
#pragma unroll
      for (int ni = 0; ni < 4; ++ni) {
        int dd = ni * 16 + (lane & 15);
        outp[(size_t)q * DMODEL + dd] = f2bf(aco[mi][ni][r] * inv);
      }
    }
}

extern "C" void kernel_launch(void* const* d_in, const int* in_sizes, int n_in,
                              void* d_out, int out_size, void* d_ws, size_t ws_size,
                              hipStream_t stream) {
  const float* x = (const float*)d_in[0];
  const float* nw = (const float*)d_in[1];
  const float* qkv_w = (const float*)d_in[2];
  const float* out_w = (const float*)d_in[3];
  float* out = (float*)d_out;

  unsigned short* ws = (unsigned short*)d_ws;
  unsigned short* xn = ws;                                   //  4M elems
  unsigned short* qkvw = xn + (size_t)MROWS * DMODEL;        //  3M
  unsigned short* outw = qkvw + (size_t)3 * DMODEL * DMODEL; //  1M
  unsigned short* qkv = outw + (size_t)DMODEL * DMODEL;      // 12M
  unsigned short* ctx = qkv + (size_t)MROWS * 3 * DMODEL;    //  4M   (total 48 MiB)

  cvt_bf16<<<dim3(3 * DMODEL * DMODEL / 1024), dim3(256), 0, stream>>>(qkv_w, qkvw, 3 * DMODEL * DMODEL / 4);
  cvt_bf16<<<dim3(DMODEL * DMODEL / 1024), dim3(256), 0, stream>>>(out_w, outw, DMODEL * DMODEL / 4);
  rmsnorm_bf16<<<dim3(MROWS), dim3(256), 0, stream>>>(x, nw, xn);
  gemm_bt<0><<<dim3(3 * DMODEL / 128, MROWS / 128), dim3(256), 0, stream>>>(xn, qkvw, qkv, MROWS, 3 * DMODEL, DMODEL);
  attn_causal<<<dim3(T_SZ / 128, B_SZ * HCNT), dim3(256), 0, stream>>>(qkv, ctx);
  gemm_bt<1><<<dim3(DMODEL / 128, MROWS / 128), dim3(256), 0, stream>>>(ctx, outw, out, MROWS, DMODEL, DMODEL);
}

// Round 2
// 188.466 us; speedup vs baseline: 1.0651x; 1.0651x over previous
//
#include <hip/hip_runtime.h>
#include <stdint.h>

#define B_SZ 2
#define T_SZ 2048
#define DMODEL 1024
#define HCNT 16
#define HD 64
#define MROWS (B_SZ * T_SZ)  // 4096

typedef __attribute__((ext_vector_type(8))) __bf16 bf16x8;
typedef __attribute__((ext_vector_type(4))) float f32x4;
typedef __attribute__((ext_vector_type(8))) unsigned short u16x8;

__device__ __forceinline__ unsigned short f2bf(float f) {
  union { float f; uint32_t u; } v; v.f = f;
  uint32_t u = v.u;
  u += 0x7fffu + ((u >> 16) & 1u);
  return (unsigned short)(u >> 16);
}

__device__ __forceinline__ void gld_lds16(const void* g, void* l) {
  __builtin_amdgcn_global_load_lds((__attribute__((address_space(1))) void*)(uintptr_t)g,
                                   (__attribute__((address_space(3))) void*)l, 16, 0, 0);
}

// ---------------- fp32 -> bf16 convert ----------------
__global__ __launch_bounds__(256)
void cvt_bf16(const float* __restrict__ in, unsigned short* __restrict__ out, int n4) {
  int i = blockIdx.x * 256 + threadIdx.x;
  if (i >= n4) return;
  float4 v = ((const float4*)in)[i];
  ushort4 o;
  o.x = f2bf(v.x); o.y = f2bf(v.y); o.z = f2bf(v.z); o.w = f2bf(v.w);
  ((ushort4*)out)[i] = o;
}

// ---------------- RMSNorm (fp32 in, bf16 out) ----------------
__global__ __launch_bounds__(256)
void rmsnorm_bf16(const float* __restrict__ x, const float* __restrict__ w,
                  unsigned short* __restrict__ xn) {
  const int row = blockIdx.x;
  const int t = threadIdx.x;
  float4 v = ((const float4*)(x + (size_t)row * DMODEL))[t];
  float ss = v.x * v.x + v.y * v.y + v.z * v.z + v.w * v.w;
#pragma unroll
  for (int o = 1; o < 64; o <<= 1) ss += __shfl_xor(ss, o, 64);
  __shared__ float red[4];
  if ((t & 63) == 0) red[t >> 6] = ss;
  __syncthreads();
  float tot = red[0] + red[1] + red[2] + red[3];
  float scale = rsqrtf(tot * (1.0f / (float)DMODEL) + 1e-6f);
  float4 wv = ((const float4*)w)[t];
  ushort4 o;
  o.x = f2bf(v.x * scale * wv.x);
  o.y = f2bf(v.y * scale * wv.y);
  o.z = f2bf(v.z * scale * wv.z);
  o.w = f2bf(v.w * scale * wv.w);
  ((ushort4*)(xn + (size_t)row * DMODEL))[t] = o;
}

// ---------------- bf16 NT GEMM: C[M][N] = A[M][K] * B[N][K]^T ----------------
__device__ __forceinline__ void stage128x32(const unsigned short* g, int ldg,
                                            unsigned short* lds, int wave, int lane) {
#pragma unroll
  for (int i = 0; i < 2; ++i) {
    const unsigned short* gp = g + (size_t)(i * 64 + wave * 16 + (lane >> 2)) * ldg + (lane & 3) * 8;
    gld_lds16(gp, lds + i * 2048 + wave * 512);
  }
}

template <int F32OUT>
__global__ __launch_bounds__(256, 2)
void gemm_bt(const unsigned short* __restrict__ A, const unsigned short* __restrict__ B,
             void* __restrict__ Cv, int M, int N, int K) {
  __shared__ __align__(16) unsigned short As[2][128 * 32];
  __shared__ __align__(16) unsigned short Bs[2][128 * 32];
  const int t = threadIdx.x, wave = t >> 6, lane = t & 63;
  const int m0 = blockIdx.y * 128, n0 = blockIdx.x * 128;
  const int wr = wave >> 1, wc = wave & 1;
  f32x4 acc[4][4] = {};
  const int nk = K >> 5;
  stage128x32(A + (size_t)m0 * K, K, As[0], wave, lane);
  stage128x32(B + (size_t)n0 * K, K, Bs[0], wave, lane);
  __syncthreads();
  int buf = 0;
  for (int kt = 0; kt < nk; ++kt) {
    if (kt + 1 < nk) {
      stage128x32(A + (size_t)m0 * K + (kt + 1) * 32, K, As[buf ^ 1], wave, lane);
      stage128x32(B + (size_t)n0 * K + (kt + 1) * 32, K, Bs[buf ^ 1], wave, lane);
    }
    bf16x8 af[4], bfr[4];
#pragma unroll
    for (int mi = 0; mi < 4; ++mi)
      af[mi] = *(const bf16x8*)&As[buf][(wr * 64 + mi * 16 + (lane & 15)) * 32 + (lane >> 4) * 8];
#pragma unroll
    for (int ni = 0; ni < 4; ++ni)
      bfr[ni] = *(const bf16x8*)&Bs[buf][(wc * 64 + ni * 16 + (lane & 15)) * 32 + (lane >> 4) * 8];
#pragma unroll
    for (int mi = 0; mi < 4; ++mi)
#pragma unroll
      for (int ni = 0; ni < 4; ++ni)
        acc[mi][ni] = __builtin_amdgcn_mfma_f32_16x16x32_bf16(af[mi], bfr[ni], acc[mi][ni], 0, 0, 0);
    __syncthreads();
    buf ^= 1;
  }
  const int cr = (lane >> 4) * 4, cc = lane & 15;
#pragma unroll
  for (int mi = 0; mi < 4; ++mi)
#pragma unroll
    for (int ni = 0; ni < 4; ++ni) {
      int row = m0 + wr * 64 + mi * 16 + cr;
      int col = n0 + wc * 64 + ni * 16 + cc;
      if (F32OUT) {
        float* C = (float*)Cv;
#pragma unroll
        for (int r = 0; r < 4; ++r) C[(size_t)(row + r) * N + col] = acc[mi][ni][r];
      } else {
        unsigned short* C = (unsigned short*)Cv;
#pragma unroll
        for (int r = 0; r < 4; ++r) C[(size_t)(row + r) * N + col] = f2bf(acc[mi][ni][r]);
      }
    }
}

// ---------------- causal flash attention (paired q-tiles, XCD-pinned) ----------
// grid: 256 blocks (1/CU), 512 threads (8 waves). Waves 0-3 own q-tile `pid`,
// waves 4-7 own mirror tile `15-pid` -> every block does 2*(16-pid) k-tiles and
// identical total compute. All blocks of one (b,h) land on one XCD (id%8) so
// K/V (512KB/bh, 2MB/XCD) stays L2-resident. Double-buffered K/V staging:
// next tile's loads are issued before current tile's compute (T3-min).
__global__ __launch_bounds__(512, 2)
void attn_causal(const unsigned short* __restrict__ qkv, unsigned short* __restrict__ ctx) {
  __shared__ __align__(16) unsigned short Ks[2][64 * 64];
  __shared__ __align__(16) unsigned short Vt[2][64 * 72];
  __shared__ __align__(16) unsigned short Pl[8][32 * 72];
  const int tid = threadIdx.x, wave = tid >> 6, lane = tid & 63;
  const int id = blockIdx.x;
  const int bh = (id & 7) + 8 * ((id >> 3) & 3);  // same bh -> same XCD
  const int pid = id >> 5;                        // 0..7
  const int b = bh >> 4, h = bh & 15;
  const int qt = (wave < 4) ? pid : (15 - pid);
  const int q0 = qt * 128 + (wave & 3) * 32;
  const size_t base = (size_t)b * T_SZ * 3 * DMODEL;
  const int koffK = DMODEL + h * HD;
  const int koffV = 2 * DMODEL + h * HD;
  const int nkb = 2 * (16 - pid);

  // hoist Q fragments (rows q0..q0+31, d=64)
  bf16x8 aq[2][2];
#pragma unroll
  for (int mi = 0; mi < 2; ++mi)
#pragma unroll
    for (int kk = 0; kk < 2; ++kk) {
      int q = q0 + mi * 16 + (lane & 15);
      aq[mi][kk] = *(const bf16x8*)(qkv + base + (size_t)q * 3 * DMODEL + h * HD + kk * 32 + (lane >> 4) * 8);
    }

  float mst[2][4], lst[2][4];
  f32x4 aco[2][4];
#pragma unroll
  for (int mi = 0; mi < 2; ++mi)
#pragma unroll
    for (int r = 0; r < 4; ++r) { mst[mi][r] = -3e38f; lst[mi][r] = 0.f; }
#pragma unroll
  for (int mi = 0; mi < 2; ++mi)
#pragma unroll
    for (int ni = 0; ni < 4; ++ni)
#pragma unroll
      for (int r = 0; r < 4; ++r) aco[mi][ni][r] = 0.f;

  const int kr = tid >> 3, kc = tid & 7;          // K staging: row, chunk
  const int kv = tid >> 3, dd0 = (tid & 7) * 8;   // V staging: row, dd base

  auto stageK = [&](int kb, int bufi) {
    // source pre-swizzled (chunk ^= row&7); LDS dest linear (wave-uniform base)
    gld_lds16(qkv + base + (size_t)(kb + kr) * 3 * DMODEL + koffK + ((kc ^ (kr & 7)) << 3),
              &Ks[bufi][wave << 9]);
  };
  auto loadV = [&](int kb) {
    return *(const u16x8*)(qkv + base + (size_t)(kb + kv) * 3 * DMODEL + koffV + dd0);
  };
  auto writeV = [&](int bufi, u16x8 v) {
#pragma unroll
    for (int j = 0; j < 8; ++j) {
      int dd = dd0 + j;
      int f = ((dd >> 4) ^ dd) & 7;  // spreads dd0 groups across banks
      Vt[bufi][dd * 72 + ((((kv >> 3) ^ f) << 3) | (kv & 7))] = v[j];
    }
  };

  auto computeTile = [&](int kb, int bufi) {
    // S = Q K^T  (32x64, K=64)
    f32x4 s[2][4] = {};
#pragma unroll
    for (int kk = 0; kk < 2; ++kk) {
      bf16x8 bk[4];
#pragma unroll
      for (int ni = 0; ni < 4; ++ni) {
        int row = ni * 16 + (lane & 15);
        int crd = kk * 4 + (lane >> 4);
        bk[ni] = *(const bf16x8*)&Ks[bufi][row * 64 + ((crd ^ (row & 7)) << 3)];
      }
#pragma unroll
      for (int mi = 0; mi < 2; ++mi)
#pragma unroll
        for (int ni = 0; ni < 4; ++ni)
          s[mi][ni] = __builtin_amdgcn_mfma_f32_16x16x32_bf16(aq[mi][kk], bk[ni], s[mi][ni], 0, 0, 0);
    }
    const bool domask = (kb + 63 > q0);
#pragma unroll
    for (int mi = 0; mi < 2; ++mi)
#pragma unroll
      for (int ni = 0; ni < 4; ++ni)
#pragma unroll
        for (int r = 0; r < 4; ++r) {
          float v = s[mi][ni][r] * 0.125f;
          if (domask) {
            int gq = q0 + mi * 16 + (lane >> 4) * 4 + r;
            int gk = kb + ni * 16 + (lane & 15);
            if (gk > gq) v = -1e30f;
          }
          s[mi][ni][r] = v;
        }
    // online softmax
#pragma unroll
    for (int mi = 0; mi < 2; ++mi)
#pragma unroll
      for (int r = 0; r < 4; ++r) {
        float rm = fmaxf(fmaxf(s[mi][0][r], s[mi][1][r]), fmaxf(s[mi][2][r], s[mi][3][r]));
        rm = fmaxf(rm, __shfl_xor(rm, 1, 16));
        rm = fmaxf(rm, __shfl_xor(rm, 2, 16));
        rm = fmaxf(rm, __shfl_xor(rm, 4, 16));
        rm = fmaxf(rm, __shfl_xor(rm, 8, 16));
        float mo = mst[mi][r];
        float mn = fmaxf(mo, rm);
        float corr = __expf(mo - mn);
        float rs = 0.f;
#pragma unroll
        for (int ni = 0; ni < 4; ++ni) {
          float p = __expf(s[mi][ni][r] - mn);
          s[mi][ni][r] = p;
          rs += p;
        }
        rs += __shfl_xor(rs, 1, 16);
        rs += __shfl_xor(rs, 2, 16);
        rs += __shfl_xor(rs, 4, 16);
        rs += __shfl_xor(rs, 8, 16);
        lst[mi][r] = lst[mi][r] * corr + rs;
        mst[mi][r] = mn;
#pragma unroll
        for (int ni = 0; ni < 4; ++ni) aco[mi][ni][r] *= corr;
      }
    // P -> per-wave LDS (bf16), then PV
    unsigned short* P = Pl[wave];
#pragma unroll
    for (int mi = 0; mi < 2; ++mi)
#pragma unroll
      for (int ni = 0; ni < 4; ++ni)
#pragma unroll
        for (int r = 0; r < 4; ++r) {
          int row = mi * 16 + (lane >> 4) * 4 + r;
          int col = ni * 16 + (lane & 15);
          P[row * 72 + col] = f2bf(s[mi][ni][r]);
        }
#pragma unroll
    for (int kk = 0; kk < 2; ++kk) {
      bf16x8 pa[2], bv[4];
#pragma unroll
      for (int mi = 0; mi < 2; ++mi)
        pa[mi] = *(const bf16x8*)&P[(mi * 16 + (lane & 15)) * 72 + kk * 32 + (lane >> 4) * 8];
#pragma unroll
      for (int ni = 0; ni < 4; ++ni) {
        int dd = ni * 16 + (lane & 15);
        int f = ((dd >> 4) ^ dd) & 7;
        int crd = kk * 4 + (lane >> 4);
        bv[ni] = *(const bf16x8*)&Vt[bufi][dd * 72 + ((crd ^ f) << 3)];
      }
#pragma unroll
      for (int mi = 0; mi < 2; ++mi)
#pragma unroll
        for (int ni = 0; ni < 4; ++ni)
          aco[mi][ni] = __builtin_amdgcn_mfma_f32_16x16x32_bf16(pa[mi], bv[ni], aco[mi][ni], 0, 0, 0);
    }
  };

  // prologue: stage tile 0
  stageK(0, 0);
  writeV(0, loadV(0));
  __syncthreads();
  int buf = 0;
  for (int t = 0; t < nkb; ++t) {
    const int kb = t * 64;
    const bool hn = (t + 1 < nkb);
    u16x8 vn;
    if (hn) {                       // issue next tile's loads before compute
      stageK(kb + 64, buf ^ 1);
      vn = loadV(kb + 64);
    }
    if (kb <= q0 + 31) computeTile(kb, buf);
    if (hn) writeV(buf ^ 1, vn);    // HBM/L2 latency hidden under compute
    __syncthreads();
    buf ^= 1;
  }

  // epilogue: O /= l, store ctx
  unsigned short* outp = ctx + (size_t)b * T_SZ * DMODEL + h * HD;
#pragma unroll
  for (int mi = 0; mi < 2; ++mi)
#pragma unroll
    for (int r = 0; r < 4; ++r) {
      int q = q0 + mi * 16 + (lane >> 4) * 4 + r;
      float inv = 1.f / lst[mi][r];
#pragma unroll
      for (int ni = 0; ni < 4; ++ni) {
        int dd = ni * 16 + (lane & 15);
        outp[(size_t)q * DMODEL + dd] = f2bf(aco[mi][ni][r] * inv);
      }
    }
}

extern "C" void kernel_launch(void* const* d_in, const int* in_sizes, int n_in,
                              void* d_out, int out_size, void* d_ws, size_t ws_size,
                              hipStream_t stream) {
  const float* x = (const float*)d_in[0];
  const float* nw = (const float*)d_in[1];
  const float* qkv_w = (const float*)d_in[2];
  const float* out_w = (const float*)d_in[3];
  float* out = (float*)d_out;

  unsigned short* ws = (unsigned short*)d_ws;
  unsigned short* xn = ws;
  unsigned short* qkvw = xn + (size_t)MROWS * DMODEL;
  unsigned short* outw = qkvw + (size_t)3 * DMODEL * DMODEL;
  unsigned short* qkv = outw + (size_t)DMODEL * DMODEL;
  unsigned short* ctx = qkv + (size_t)MROWS * 3 * DMODEL;

  cvt_bf16<<<dim3(3 * DMODEL * DMODEL / 1024), dim3(256), 0, stream>>>(qkv_w, qkvw, 3 * DMODEL * DMODEL / 4);
  cvt_bf16<<<dim3(DMODEL * DMODEL / 1024), dim3(256), 0, stream>>>(out_w, outw, DMODEL * DMODEL / 4);
  rmsnorm_bf16<<<dim3(MROWS), dim3(256), 0, stream>>>(x, nw, xn);
  gemm_bt<0><<<dim3(3 * DMODEL / 128, MROWS / 128), dim3(256), 0, stream>>>(xn, qkvw, qkv, MROWS, 3 * DMODEL, DMODEL);
  attn_causal<<<dim3(256), dim3(512), 0, stream>>>(qkv, ctx);
  gemm_bt<1><<<dim3(DMODEL / 128, MROWS / 128), dim3(256), 0, stream>>>(ctx, outw, out, MROWS, DMODEL, DMODEL);
}

// Round 3
// 136.963 us; speedup vs baseline: 1.4657x; 1.3760x over previous
//
#include <hip/hip_runtime.h>
#include <stdint.h>

#define B_SZ 2
#define T_SZ 2048
#define DMODEL 1024
#define HCNT 16
#define HD 64
#define MROWS (B_SZ * T_SZ)  // 4096

typedef __attribute__((ext_vector_type(8))) __bf16 bf16x8;
typedef __attribute__((ext_vector_type(4))) __bf16 bf16x4;
typedef __attribute__((ext_vector_type(4))) float f32x4;
typedef __attribute__((ext_vector_type(8))) unsigned short u16x8;

__device__ __forceinline__ unsigned short f2bf(float f) {
  union { float f; uint32_t u; } v; v.f = f;
  uint32_t u = v.u;
  u += 0x7fffu + ((u >> 16) & 1u);
  return (unsigned short)(u >> 16);
}

__device__ __forceinline__ void gld_lds16(const void* g, void* l) {
  __builtin_amdgcn_global_load_lds((__attribute__((address_space(1))) void*)(uintptr_t)g,
                                   (__attribute__((address_space(3))) void*)l, 16, 0, 0);
}

// ---------------- fp32 -> bf16 convert ----------------
__global__ __launch_bounds__(256)
void cvt_bf16(const float* __restrict__ in, unsigned short* __restrict__ out, int n4) {
  int i = blockIdx.x * 256 + threadIdx.x;
  if (i >= n4) return;
  float4 v = ((const float4*)in)[i];
  ushort4 o;
  o.x = f2bf(v.x); o.y = f2bf(v.y); o.z = f2bf(v.z); o.w = f2bf(v.w);
  ((ushort4*)out)[i] = o;
}

// ---------------- RMSNorm (fp32 in, bf16 out) ----------------
__global__ __launch_bounds__(256)
void rmsnorm_bf16(const float* __restrict__ x, const float* __restrict__ w,
                  unsigned short* __restrict__ xn) {
  const int row = blockIdx.x;
  const int t = threadIdx.x;
  float4 v = ((const float4*)(x + (size_t)row * DMODEL))[t];
  float ss = v.x * v.x + v.y * v.y + v.z * v.z + v.w * v.w;
#pragma unroll
  for (int o = 1; o < 64; o <<= 1) ss += __shfl_xor(ss, o, 64);
  __shared__ float red[4];
  if ((t & 63) == 0) red[t >> 6] = ss;
  __syncthreads();
  float tot = red[0] + red[1] + red[2] + red[3];
  float scale = rsqrtf(tot * (1.0f / (float)DMODEL) + 1e-6f);
  float4 wv = ((const float4*)w)[t];
  ushort4 o;
  o.x = f2bf(v.x * scale * wv.x);
  o.y = f2bf(v.y * scale * wv.y);
  o.z = f2bf(v.z * scale * wv.z);
  o.w = f2bf(v.w * scale * wv.w);
  ((ushort4*)(xn + (size_t)row * DMODEL))[t] = o;
}

// ---------------- bf16 NT GEMM: C[M][N] = A[M][K] * B[N][K]^T ----------------
__device__ __forceinline__ void stage128x32(const unsigned short* g, int ldg,
                                            unsigned short* lds, int wave, int lane) {
#pragma unroll
  for (int i = 0; i < 2; ++i) {
    const unsigned short* gp = g + (size_t)(i * 64 + wave * 16 + (lane >> 2)) * ldg + (lane & 3) * 8;
    gld_lds16(gp, lds + i * 2048 + wave * 512);
  }
}

template <int F32OUT>
__global__ __launch_bounds__(256, 2)
void gemm_bt(const unsigned short* __restrict__ A, const unsigned short* __restrict__ B,
             void* __restrict__ Cv, int M, int N, int K) {
  __shared__ __align__(16) unsigned short As[2][128 * 32];
  __shared__ __align__(16) unsigned short Bs[2][128 * 32];
  const int t = threadIdx.x, wave = t >> 6, lane = t & 63;
  const int m0 = blockIdx.y * 128, n0 = blockIdx.x * 128;
  const int wr = wave >> 1, wc = wave & 1;
  f32x4 acc[4][4] = {};
  const int nk = K >> 5;
  stage128x32(A + (size_t)m0 * K, K, As[0], wave, lane);
  stage128x32(B + (size_t)n0 * K, K, Bs[0], wave, lane);
  __syncthreads();
  int buf = 0;
  for (int kt = 0; kt < nk; ++kt) {
    if (kt + 1 < nk) {
      stage128x32(A + (size_t)m0 * K + (kt + 1) * 32, K, As[buf ^ 1], wave, lane);
      stage128x32(B + (size_t)n0 * K + (kt + 1) * 32, K, Bs[buf ^ 1], wave, lane);
    }
    bf16x8 af[4], bfr[4];
#pragma unroll
    for (int mi = 0; mi < 4; ++mi)
      af[mi] = *(const bf16x8*)&As[buf][(wr * 64 + mi * 16 + (lane & 15)) * 32 + (lane >> 4) * 8];
#pragma unroll
    for (int ni = 0; ni < 4; ++ni)
      bfr[ni] = *(const bf16x8*)&Bs[buf][(wc * 64 + ni * 16 + (lane & 15)) * 32 + (lane >> 4) * 8];
#pragma unroll
    for (int mi = 0; mi < 4; ++mi)
#pragma unroll
      for (int ni = 0; ni < 4; ++ni)
        acc[mi][ni] = __builtin_amdgcn_mfma_f32_16x16x32_bf16(af[mi], bfr[ni], acc[mi][ni], 0, 0, 0);
    __syncthreads();
    buf ^= 1;
  }
  const int cr = (lane >> 4) * 4, cc = lane & 15;
#pragma unroll
  for (int mi = 0; mi < 4; ++mi)
#pragma unroll
    for (int ni = 0; ni < 4; ++ni) {
      int row = m0 + wr * 64 + mi * 16 + cr;
      int col = n0 + wc * 64 + ni * 16 + cc;
      if (F32OUT) {
        float* C = (float*)Cv;
#pragma unroll
        for (int r = 0; r < 4; ++r) C[(size_t)(row + r) * N + col] = acc[mi][ni][r];
      } else {
        unsigned short* C = (unsigned short*)Cv;
#pragma unroll
        for (int r = 0; r < 4; ++r) C[(size_t)(row + r) * N + col] = f2bf(acc[mi][ni][r]);
      }
    }
}

// ---------------- causal flash attention v3 ----------------
// 256 threads (4 waves x 32 q-rows = 128-row q-tile). Grid 512, XCD-pinned
// (id&7), big-first ordering: block i and i+256 share a CU, k-tile counts sum
// to 34 -> balanced. Swapped QK^T (S^T in regs): softmax row is lane-local
// (2 shfls), P-store is ds_write_b64, PV A-frag read is b128 conflict-free.
__global__ __launch_bounds__(256, 2)
void attn_causal(const unsigned short* __restrict__ qkv, unsigned short* __restrict__ ctx) {
  __shared__ __align__(16) unsigned short Ks[2][64 * 64];
  __shared__ __align__(16) unsigned short Vt[2][64 * 72];
  __shared__ __align__(16) unsigned short Pl[4][32 * 72];
  const int tid = threadIdx.x, wave = tid >> 6, lane = tid & 63;
  const int id = blockIdx.x;
  const int bh = (id & 7) + 8 * ((id >> 3) & 3);
  const int m = id >> 5;                       // 0..15
  const int qt = (m < 8) ? (15 - m) : (m - 8); // big-first, then small ascending
  const int b = bh >> 4, h = bh & 15;
  const int q0 = qt * 128 + wave * 32;
  const size_t base = (size_t)b * T_SZ * 3 * DMODEL;
  const int koffK = DMODEL + h * HD;
  const int koffV = 2 * DMODEL + h * HD;
  const int nkb = 2 * (qt + 1);
  const int c = lane & 15, qg = lane >> 4;

  // Q fragments (B-operand): rows q0..q0+31, d=64
  bf16x8 aq[2][2];
#pragma unroll
  for (int mi = 0; mi < 2; ++mi)
#pragma unroll
    for (int kk = 0; kk < 2; ++kk) {
      int q = q0 + mi * 16 + c;
      aq[mi][kk] = *(const bf16x8*)(qkv + base + (size_t)q * 3 * DMODEL + h * HD + kk * 32 + qg * 8);
    }

  float mst[2] = {-3e38f, -3e38f}, lst[2] = {0.f, 0.f};
  f32x4 aco[2][4];
#pragma unroll
  for (int mi = 0; mi < 2; ++mi)
#pragma unroll
    for (int nd = 0; nd < 4; ++nd)
#pragma unroll
      for (int r = 0; r < 4; ++r) aco[mi][nd][r] = 0.f;

  const int kr = tid >> 3;   // 0..31
  const int kc = tid & 7;

  auto stageK = [&](int kb, int bufi) {
#pragma unroll
    for (int i = 0; i < 2; ++i) {
      int row = i * 32 + kr;
      gld_lds16(qkv + base + (size_t)(kb + row) * 3 * DMODEL + koffK + ((kc ^ (row & 7)) << 3),
                &Ks[bufi][i * 2048 + (wave << 9)]);
    }
  };
  auto loadV = [&](int kb, u16x8* v) {
#pragma unroll
    for (int i = 0; i < 2; ++i)
      v[i] = *(const u16x8*)(qkv + base + (size_t)(kb + i * 32 + kr) * 3 * DMODEL + koffV + kc * 8);
  };
  auto writeV = [&](int bufi, const u16x8* v) {
#pragma unroll
    for (int i = 0; i < 2; ++i) {
      int kv = i * 32 + kr;
#pragma unroll
      for (int j = 0; j < 8; ++j) {
        int dd = kc * 8 + j;
        int f = ((dd >> 3) ^ dd) & 7;   // = kc ^ j
        Vt[bufi][dd * 72 + ((((kv >> 3) ^ f) << 3) | (kv & 7))] = v[i][j];
      }
    }
  };

  auto computeTile = [&](int kb, int bufi) {
    // S^T = K Q^T : s[ni][mi], k-row = 16ni + 4qg + r, q-col = 16mi + c
    f32x4 s[4][2] = {};
#pragma unroll
    for (int kk = 0; kk < 2; ++kk) {
      bf16x8 bk[4];
#pragma unroll
      for (int ni = 0; ni < 4; ++ni) {
        int row = ni * 16 + c;
        int crd = kk * 4 + qg;
        bk[ni] = *(const bf16x8*)&Ks[bufi][row * 64 + ((crd ^ (row & 7)) << 3)];
      }
#pragma unroll
      for (int ni = 0; ni < 4; ++ni)
#pragma unroll
        for (int mi = 0; mi < 2; ++mi)
          s[ni][mi] = __builtin_amdgcn_mfma_f32_16x16x32_bf16(bk[ni], aq[mi][kk], s[ni][mi], 0, 0, 0);
    }
    const bool domask = (kb + 63 > q0);
#pragma unroll
    for (int ni = 0; ni < 4; ++ni)
#pragma unroll
      for (int mi = 0; mi < 2; ++mi)
#pragma unroll
        for (int r = 0; r < 4; ++r) {
          float v = s[ni][mi][r] * 0.125f;
          if (domask) {
            int kg = kb + ni * 16 + qg * 4 + r;
            int qq = q0 + mi * 16 + c;
            if (kg > qq) v = -1e30f;
          }
          s[ni][mi][r] = v;
        }
    // online softmax: row = q0 + 16mi + c (lane-local), reduce in-lane + 2 shfls
    float crr[2][4];
#pragma unroll
    for (int mi = 0; mi < 2; ++mi) {
      float rm = -3e38f;
#pragma unroll
      for (int ni = 0; ni < 4; ++ni)
#pragma unroll
        for (int r = 0; r < 4; ++r) rm = fmaxf(rm, s[ni][mi][r]);
      rm = fmaxf(rm, __shfl_xor(rm, 16, 64));
      rm = fmaxf(rm, __shfl_xor(rm, 32, 64));
      float mo = mst[mi];
      float mn = fmaxf(mo, rm);
      float corr = __expf(mo - mn);
      float rs = 0.f;
#pragma unroll
      for (int ni = 0; ni < 4; ++ni)
#pragma unroll
        for (int r = 0; r < 4; ++r) {
          float p = __expf(s[ni][mi][r] - mn);
          s[ni][mi][r] = p;
          rs += p;
        }
      rs += __shfl_xor(rs, 16, 64);
      rs += __shfl_xor(rs, 32, 64);
      lst[mi] = lst[mi] * corr + rs;
      mst[mi] = mn;
      // broadcast corr to aco's row layout (row = 16mi + 4qg + r)
#pragma unroll
      for (int r = 0; r < 4; ++r)
        crr[mi][r] = __shfl(corr, qg * 20 + r, 64);
    }
#pragma unroll
    for (int mi = 0; mi < 2; ++mi)
#pragma unroll
      for (int nd = 0; nd < 4; ++nd)
#pragma unroll
        for (int r = 0; r < 4; ++r) aco[mi][nd][r] *= crr[mi][r];
    // P -> LDS: 4 consecutive k per lane -> b64 stores (conflict-free)
    unsigned short* P = Pl[wave];
#pragma unroll
    for (int ni = 0; ni < 4; ++ni)
#pragma unroll
      for (int mi = 0; mi < 2; ++mi) {
        bf16x4 pk;
#pragma unroll
        for (int r = 0; r < 4; ++r) pk[r] = (__bf16)s[ni][mi][r];
        *(bf16x4*)&P[(mi * 16 + c) * 72 + ni * 16 + qg * 4] = pk;
      }
    // PV: O += P[32x64] * V[64x64]
#pragma unroll
    for (int kk = 0; kk < 2; ++kk) {
      bf16x8 pa[2], bv[4];
#pragma unroll
      for (int mi = 0; mi < 2; ++mi)
        pa[mi] = *(const bf16x8*)&P[(mi * 16 + c) * 72 + kk * 32 + qg * 8];
#pragma unroll
      for (int nd = 0; nd < 4; ++nd) {
        int dd = nd * 16 + c;
        int f = ((dd >> 3) ^ dd) & 7;
        int crd = kk * 4 + qg;
        bv[nd] = *(const bf16x8*)&Vt[bufi][dd * 72 + ((crd ^ f) << 3)];
      }
#pragma unroll
      for (int mi = 0; mi < 2; ++mi)
#pragma unroll
        for (int nd = 0; nd < 4; ++nd)
          aco[mi][nd] = __builtin_amdgcn_mfma_f32_16x16x32_bf16(pa[mi], bv[nd], aco[mi][nd], 0, 0, 0);
    }
  };

  // prologue
  stageK(0, 0);
  u16x8 v0[2];
  loadV(0, v0);
  writeV(0, v0);
  __syncthreads();
  int buf = 0;
  for (int t = 0; t < nkb; ++t) {
    const int kb = t * 64;
    const bool hn = (t + 1 < nkb);
    u16x8 vn[2];
    if (hn) { stageK(kb + 64, buf ^ 1); loadV(kb + 64, vn); }
    if (kb <= q0 + 31) computeTile(kb, buf);
    if (hn) writeV(buf ^ 1, vn);
    __syncthreads();
    buf ^= 1;
  }

  // epilogue: O /= l  (row = q0 + 16mi + 4qg + r)
  unsigned short* outp = ctx + (size_t)b * T_SZ * DMODEL + h * HD;
#pragma unroll
  for (int mi = 0; mi < 2; ++mi) {
    float linv = 1.f / lst[mi];
#pragma unroll
    for (int r = 0; r < 4; ++r) {
      float inv = __shfl(linv, qg * 20 + r, 64);
      int q = q0 + mi * 16 + qg * 4 + r;
#pragma unroll
      for (int nd = 0; nd < 4; ++nd)
        outp[(size_t)q * DMODEL + nd * 16 + c] = f2bf(aco[mi][nd][r] * inv);
    }
  }
}

extern "C" void kernel_launch(void* const* d_in, const int* in_sizes, int n_in,
                              void* d_out, int out_size, void* d_ws, size_t ws_size,
                              hipStream_t stream) {
  const float* x = (const float*)d_in[0];
  const float* nw = (const float*)d_in[1];
  const float* qkv_w = (const float*)d_in[2];
  const float* out_w = (const float*)d_in[3];
  float* out = (float*)d_out;

  unsigned short* ws = (unsigned short*)d_ws;
  unsigned short* xn = ws;
  unsigned short* qkvw = xn + (size_t)MROWS * DMODEL;
  unsigned short* outw = qkvw + (size_t)3 * DMODEL * DMODEL;
  unsigned short* qkv = outw + (size_t)DMODEL * DMODEL;
  unsigned short* ctx = qkv + (size_t)MROWS * 3 * DMODEL;

  cvt_bf16<<<dim3(3 * DMODEL * DMODEL / 1024), dim3(256), 0, stream>>>(qkv_w, qkvw, 3 * DMODEL * DMODEL / 4);
  cvt_bf16<<<dim3(DMODEL * DMODEL / 1024), dim3(256), 0, stream>>>(out_w, outw, DMODEL * DMODEL / 4);
  rmsnorm_bf16<<<dim3(MROWS), dim3(256), 0, stream>>>(x, nw, xn);
  gemm_bt<0><<<dim3(3 * DMODEL / 128, MROWS / 128), dim3(256), 0, stream>>>(xn, qkvw, qkv, MROWS, 3 * DMODEL, DMODEL);
  attn_causal<<<dim3(512), dim3(256), 0, stream>>>(qkv, ctx);
  gemm_bt<1><<<dim3(DMODEL / 128, MROWS / 128), dim3(256), 0, stream>>>(ctx, outw, out, MROWS, DMODEL, DMODEL);
}

// Round 4
// 121.144 us; speedup vs baseline: 1.6571x; 1.1306x over previous
//
#include <hip/hip_runtime.h>
#include <stdint.h>

#define B_SZ 2
#define T_SZ 2048
#define DMODEL 1024
#define HCNT 16
#define HD 64
#define MROWS (B_SZ * T_SZ)  // 4096

typedef __attribute__((ext_vector_type(8))) __bf16 bf16x8;
typedef __attribute__((ext_vector_type(4))) __bf16 bf16x4;
typedef __attribute__((ext_vector_type(4))) float f32x4;
typedef __attribute__((ext_vector_type(8))) unsigned short u16x8;

__device__ __forceinline__ unsigned short f2bf(float f) {
  union { float f; uint32_t u; } v; v.f = f;
  uint32_t u = v.u;
  u += 0x7fffu + ((u >> 16) & 1u);
  return (unsigned short)(u >> 16);
}

__device__ __forceinline__ float fexp2(float x) {
#if __has_builtin(__builtin_amdgcn_exp2f)
  return __builtin_amdgcn_exp2f(x);
#else
  return exp2f(x);
#endif
}

__device__ __forceinline__ void gld_lds16(const void* g, void* l) {
  __builtin_amdgcn_global_load_lds((__attribute__((address_space(1))) void*)(uintptr_t)g,
                                   (__attribute__((address_space(3))) void*)l, 16, 0, 0);
}

// ---------------- fp32 -> bf16 convert (both weight tensors, one launch) ----
__global__ __launch_bounds__(256)
void cvt_all(const float* __restrict__ qkv_w, const float* __restrict__ out_w,
             unsigned short* __restrict__ dst) {  // dst = qkvw; outw contiguous after
  int i = blockIdx.x * 256 + threadIdx.x;        // over 1M float4 groups
  const int n1 = 3 * DMODEL * DMODEL / 4;
  float4 v = (i < n1) ? ((const float4*)qkv_w)[i] : ((const float4*)out_w)[i - n1];
  ushort4 o;
  o.x = f2bf(v.x); o.y = f2bf(v.y); o.z = f2bf(v.z); o.w = f2bf(v.w);
  ((ushort4*)dst)[i] = o;
}

// ---------------- RMSNorm (fp32 in, bf16 out) ----------------
__global__ __launch_bounds__(256)
void rmsnorm_bf16(const float* __restrict__ x, const float* __restrict__ w,
                  unsigned short* __restrict__ xn) {
  const int row = blockIdx.x;
  const int t = threadIdx.x;
  float4 v = ((const float4*)(x + (size_t)row * DMODEL))[t];
  float ss = v.x * v.x + v.y * v.y + v.z * v.z + v.w * v.w;
#pragma unroll
  for (int o = 1; o < 64; o <<= 1) ss += __shfl_xor(ss, o, 64);
  __shared__ float red[4];
  if ((t & 63) == 0) red[t >> 6] = ss;
  __syncthreads();
  float tot = red[0] + red[1] + red[2] + red[3];
  float scale = rsqrtf(tot * (1.0f / (float)DMODEL) + 1e-6f);
  float4 wv = ((const float4*)w)[t];
  ushort4 o;
  o.x = f2bf(v.x * scale * wv.x);
  o.y = f2bf(v.y * scale * wv.y);
  o.z = f2bf(v.z * scale * wv.z);
  o.w = f2bf(v.w * scale * wv.w);
  ((ushort4*)(xn + (size_t)row * DMODEL))[t] = o;
}

// ---------------- bf16 NT GEMM: C[M][N] = A[M][K] * B[N][K]^T ----------------
// flat grid + bijective XCD swizzle (nwg % 8 == 0): XCD x gets a contiguous
// tile range -> A-panels L2-resident per XCD.
__device__ __forceinline__ void stage128x32(const unsigned short* g, int ldg,
                                            unsigned short* lds, int wave, int lane) {
#pragma unroll
  for (int i = 0; i < 2; ++i) {
    const unsigned short* gp = g + (size_t)(i * 64 + wave * 16 + (lane >> 2)) * ldg + (lane & 3) * 8;
    gld_lds16(gp, lds + i * 2048 + wave * 512);
  }
}

template <int F32OUT>
__global__ __launch_bounds__(256, 2)
void gemm_bt(const unsigned short* __restrict__ A, const unsigned short* __restrict__ B,
             void* __restrict__ Cv, int M, int N, int K, int nbx) {
  __shared__ __align__(16) unsigned short As[2][128 * 32];
  __shared__ __align__(16) unsigned short Bs[2][128 * 32];
  const int t = threadIdx.x, wave = t >> 6, lane = t & 63;
  const int cpx = gridDim.x >> 3;
  const int swz = (blockIdx.x & 7) * cpx + (blockIdx.x >> 3);
  const int m0 = (swz / nbx) * 128, n0 = (swz % nbx) * 128;
  const int wr = wave >> 1, wc = wave & 1;
  f32x4 acc[4][4] = {};
  const int nk = K >> 5;
  stage128x32(A + (size_t)m0 * K, K, As[0], wave, lane);
  stage128x32(B + (size_t)n0 * K, K, Bs[0], wave, lane);
  __syncthreads();
  int buf = 0;
  for (int kt = 0; kt < nk; ++kt) {
    if (kt + 1 < nk) {
      stage128x32(A + (size_t)m0 * K + (kt + 1) * 32, K, As[buf ^ 1], wave, lane);
      stage128x32(B + (size_t)n0 * K + (kt + 1) * 32, K, Bs[buf ^ 1], wave, lane);
    }
    bf16x8 af[4], bfr[4];
#pragma unroll
    for (int mi = 0; mi < 4; ++mi)
      af[mi] = *(const bf16x8*)&As[buf][(wr * 64 + mi * 16 + (lane & 15)) * 32 + (lane >> 4) * 8];
#pragma unroll
    for (int ni = 0; ni < 4; ++ni)
      bfr[ni] = *(const bf16x8*)&Bs[buf][(wc * 64 + ni * 16 + (lane & 15)) * 32 + (lane >> 4) * 8];
#pragma unroll
    for (int mi = 0; mi < 4; ++mi)
#pragma unroll
      for (int ni = 0; ni < 4; ++ni)
        acc[mi][ni] = __builtin_amdgcn_mfma_f32_16x16x32_bf16(af[mi], bfr[ni], acc[mi][ni], 0, 0, 0);
    __syncthreads();
    buf ^= 1;
  }
  const int cr = (lane >> 4) * 4, cc = lane & 15;
#pragma unroll
  for (int mi = 0; mi < 4; ++mi)
#pragma unroll
    for (int ni = 0; ni < 4; ++ni) {
      int row = m0 + wr * 64 + mi * 16 + cr;
      int col = n0 + wc * 64 + ni * 16 + cc;
      if (F32OUT) {
        float* C = (float*)Cv;
#pragma unroll
        for (int r = 0; r < 4; ++r) C[(size_t)(row + r) * N + col] = acc[mi][ni][r];
      } else {
        unsigned short* C = (unsigned short*)Cv;
#pragma unroll
        for (int r = 0; r < 4; ++r) C[(size_t)(row + r) * N + col] = f2bf(acc[mi][ni][r]);
      }
    }
}

// ---------------- causal flash attention v4: KVBLK=128 ----------------
// 512 blocks x 256 threads (4 waves x 32 q-rows = 128-row q-tile), XCD-pinned,
// paired big/small tiles on each CU (blocks i, i+256 -> 17 iters combined).
// K double-buffered via global_load_lds; V reg-staged (T14) into a single
// transposed LDS buffer; P reused across the two 64-col chunks.
// Softmax in log2 domain (scale folded into Q), defer-max (T13), setprio (T5).
__global__ __launch_bounds__(256, 2)
void attn_causal(const unsigned short* __restrict__ qkv, unsigned short* __restrict__ ctx) {
  __shared__ __align__(16) unsigned short Ks[2][128 * 64];  // 32 KB
  __shared__ __align__(16) unsigned short Vt[2][64 * 72];   // 18.4 KB (chunk 0/1)
  __shared__ __align__(16) unsigned short Pl[4][32 * 72];   // 18.4 KB
  const int tid = threadIdx.x, wave = tid >> 6, lane = tid & 63;
  const int id = blockIdx.x;
  const int bh = (id & 7) + 8 * ((id >> 3) & 3);
  const int p = id >> 5;                        // 0..15
  const int qt = (p < 8) ? (15 - p) : (p - 8);  // big-first; pairs sum to 17 iters
  const int b = bh >> 4, h = bh & 15;
  const int q0 = qt * 128 + wave * 32;
  const size_t base = (size_t)b * T_SZ * 3 * DMODEL;
  const int koffK = DMODEL + h * HD;
  const int koffV = 2 * DMODEL + h * HD;
  const int nit = qt + 1;
  const int c = lane & 15, qg = lane >> 4;

  // Q fragments, pre-scaled by 0.125 * log2(e)
  const float QSC = 0.125f * 1.4426950408889634f;
  bf16x8 aq[2][2];
#pragma unroll
  for (int mi = 0; mi < 2; ++mi)
#pragma unroll
    for (int kk = 0; kk < 2; ++kk) {
      int q = q0 + mi * 16 + c;
      bf16x8 f = *(const bf16x8*)(qkv + base + (size_t)q * 3 * DMODEL + h * HD + kk * 32 + qg * 8);
#pragma unroll
      for (int j = 0; j < 8; ++j) f[j] = (__bf16)((float)f[j] * QSC);
      aq[mi][kk] = f;
    }

  float mst[2] = {-3e38f, -3e38f}, lst[2] = {0.f, 0.f};
  f32x4 aco[2][4];
#pragma unroll
  for (int mi = 0; mi < 2; ++mi)
#pragma unroll
    for (int nd = 0; nd < 4; ++nd)
#pragma unroll
      for (int r = 0; r < 4; ++r) aco[mi][nd][r] = 0.f;

  const int kr = tid >> 3;   // 0..31
  const int kc = tid & 7;

  auto stageK = [&](int kb, int bufi) {
#pragma unroll
    for (int i = 0; i < 4; ++i) {
      int row = i * 32 + kr;
      gld_lds16(qkv + base + (size_t)(kb + row) * 3 * DMODEL + koffK + ((kc ^ (row & 7)) << 3),
                &Ks[bufi][i * 2048 + (wave << 9)]);
    }
  };
  auto loadV = [&](int kb, u16x8* v) {
#pragma unroll
    for (int i = 0; i < 4; ++i)
      v[i] = *(const u16x8*)(qkv + base + (size_t)(kb + i * 32 + kr) * 3 * DMODEL + koffV + kc * 8);
  };
  auto writeV = [&](const u16x8* v) {
#pragma unroll
    for (int i = 0; i < 4; ++i) {
      int ch = i >> 1;
      int kv = (i & 1) * 32 + kr;
#pragma unroll
      for (int j = 0; j < 8; ++j) {
        int dd = kc * 8 + j;
        int f = kc ^ j;  // ((dd>>3)^dd)&7
        Vt[ch][dd * 72 + ((((kv >> 3) ^ f) << 3) | (kv & 7))] = v[i][j];
      }
    }
  };

  auto computeTile = [&](int kb, int kbuf) {
    // S^T = K Q^T : s[ni][mi], k-row = kb + 16ni + 4qg + r, q-col = q0 + 16mi + c
    f32x4 s[8][2] = {};
    __builtin_amdgcn_s_setprio(1);
#pragma unroll
    for (int kk = 0; kk < 2; ++kk) {
      bf16x8 bk[8];
#pragma unroll
      for (int ni = 0; ni < 8; ++ni) {
        int row = ni * 16 + c;
        int crd = kk * 4 + qg;
        bk[ni] = *(const bf16x8*)&Ks[kbuf][row * 64 + ((crd ^ (row & 7)) << 3)];
      }
#pragma unroll
      for (int ni = 0; ni < 8; ++ni)
#pragma unroll
        for (int mi = 0; mi < 2; ++mi)
          s[ni][mi] = __builtin_amdgcn_mfma_f32_16x16x32_bf16(bk[ni], aq[mi][kk], s[ni][mi], 0, 0, 0);
    }
    __builtin_amdgcn_s_setprio(0);
    // causal mask: only the diagonal (last) iteration needs it
    if (kb + 127 > q0) {
#pragma unroll
      for (int ni = 0; ni < 8; ++ni)
#pragma unroll
        for (int mi = 0; mi < 2; ++mi)
#pragma unroll
          for (int r = 0; r < 4; ++r) {
            int kg = kb + ni * 16 + qg * 4 + r;
            int qq = q0 + mi * 16 + c;
            if (kg > qq) s[ni][mi][r] = -1e30f;
          }
    }
    // online softmax (log2 domain), defer-max
#pragma unroll
    for (int mi = 0; mi < 2; ++mi) {
      float rm = -3e38f;
#pragma unroll
      for (int ni = 0; ni < 8; ++ni)
#pragma unroll
        for (int r = 0; r < 4; ++r) rm = fmaxf(rm, s[ni][mi][r]);
      rm = fmaxf(rm, __shfl_xor(rm, 16, 64));
      rm = fmaxf(rm, __shfl_xor(rm, 32, 64));
      float mo = mst[mi];
      float mn = mo;
      if (__any(rm > mo + 11.5f)) {   // wave-uniform rescale path
        mn = fmaxf(mo, rm);
        float corr = fexp2(mo - mn);
        lst[mi] *= corr;
        mst[mi] = mn;
#pragma unroll
        for (int r = 0; r < 4; ++r) {
          float cr = __shfl(corr, qg * 20 + r, 64);  // corr of row offset 4qg+r
#pragma unroll
          for (int nd = 0; nd < 4; ++nd) aco[mi][nd][r] *= cr;
        }
      }
      float rs = 0.f;
#pragma unroll
      for (int ni = 0; ni < 8; ++ni)
#pragma unroll
        for (int r = 0; r < 4; ++r) {
          float pv = fexp2(s[ni][mi][r] - mn);
          s[ni][mi][r] = pv;
          rs += pv;
        }
      rs += __shfl_xor(rs, 16, 64);
      rs += __shfl_xor(rs, 32, 64);
      lst[mi] += rs;
    }
    // P -> LDS and PV, per 64-col chunk (P buffer reused across chunks)
    unsigned short* P = Pl[wave];
#pragma unroll
    for (int ch = 0; ch < 2; ++ch) {
      if (ch == 1) {  // ensure chunk-0 pa reads completed before overwrite
        asm volatile("s_waitcnt lgkmcnt(0)" ::: "memory");
        __builtin_amdgcn_sched_barrier(0);
      }
#pragma unroll
      for (int n2 = 0; n2 < 4; ++n2) {
        int ni = ch * 4 + n2;
#pragma unroll
        for (int mi = 0; mi < 2; ++mi) {
          bf16x4 pk;
#pragma unroll
          for (int r = 0; r < 4; ++r) pk[r] = (__bf16)s[ni][mi][r];
          *(bf16x4*)&P[(mi * 16 + c) * 72 + n2 * 16 + qg * 4] = pk;
        }
      }
      __builtin_amdgcn_s_setprio(1);
#pragma unroll
      for (int kk = 0; kk < 2; ++kk) {
        bf16x8 pa[2], bv[4];
#pragma unroll
        for (int mi = 0; mi < 2; ++mi)
          pa[mi] = *(const bf16x8*)&P[(mi * 16 + c) * 72 + kk * 32 + qg * 8];
#pragma unroll
        for (int nd = 0; nd < 4; ++nd) {
          int dd = nd * 16 + c;
          int f = ((dd >> 3) ^ dd) & 7;
          int crd = kk * 4 + qg;
          bv[nd] = *(const bf16x8*)&Vt[ch][dd * 72 + ((crd ^ f) << 3)];
        }
#pragma unroll
        for (int mi = 0; mi < 2; ++mi)
#pragma unroll
          for (int nd = 0; nd < 4; ++nd)
            aco[mi][nd] = __builtin_amdgcn_mfma_f32_16x16x32_bf16(pa[mi], bv[nd], aco[mi][nd], 0, 0, 0);
      }
      __builtin_amdgcn_s_setprio(0);
    }
  };

  // prologue: tile 0
  stageK(0, 0);
  u16x8 v0[4];
  loadV(0, v0);
  __syncthreads();   // drains K stage + V loads
  writeV(v0);
  __syncthreads();   // Vt ready
  int kbuf = 0;
  for (int t = 0; t < nit; ++t) {
    const int kb = t * 128;
    const bool hn = (t + 1 < nit);
    u16x8 vn[4];
    if (hn) { stageK(kb + 128, kbuf ^ 1); loadV(kb + 128, vn); }
    computeTile(kb, kbuf);
    __syncthreads();                 // all waves done with Vt/P; drains prefetches
    if (hn) writeV(vn);
    __syncthreads();                 // Vt holds tile t+1
    kbuf ^= 1;
  }

  // epilogue: O /= l  (row = q0 + 16mi + 4qg + r)
  unsigned short* outp = ctx + (size_t)b * T_SZ * DMODEL + h * HD;
#pragma unroll
  for (int mi = 0; mi < 2; ++mi) {
    float linv = 1.f / lst[mi];
#pragma unroll
    for (int r = 0; r < 4; ++r) {
      float inv = __shfl(linv, qg * 20 + r, 64);
      int q = q0 + mi * 16 + qg * 4 + r;
#pragma unroll
      for (int nd = 0; nd < 4; ++nd)
        outp[(size_t)q * DMODEL + nd * 16 + c] = f2bf(aco[mi][nd][r] * inv);
    }
  }
}

extern "C" void kernel_launch(void* const* d_in, const int* in_sizes, int n_in,
                              void* d_out, int out_size, void* d_ws, size_t ws_size,
                              hipStream_t stream) {
  const float* x = (const float*)d_in[0];
  const float* nw = (const float*)d_in[1];
  const float* qkv_w = (const float*)d_in[2];
  const float* out_w = (const float*)d_in[3];
  float* out = (float*)d_out;

  unsigned short* ws = (unsigned short*)d_ws;
  unsigned short* xn = ws;                                   //  4M elems
  unsigned short* qkvw = xn + (size_t)MROWS * DMODEL;        //  3M
  unsigned short* outw = qkvw + (size_t)3 * DMODEL * DMODEL; //  1M (contiguous after qkvw)
  unsigned short* qkv = outw + (size_t)DMODEL * DMODEL;      // 12M
  unsigned short* ctx = qkv + (size_t)MROWS * 3 * DMODEL;    //  4M

  cvt_all<<<dim3(4096), dim3(256), 0, stream>>>(qkv_w, out_w, qkvw);
  rmsnorm_bf16<<<dim3(MROWS), dim3(256), 0, stream>>>(x, nw, xn);
  gemm_bt<0><<<dim3(768), dim3(256), 0, stream>>>(xn, qkvw, qkv, MROWS, 3 * DMODEL, DMODEL, 24);
  attn_causal<<<dim3(512), dim3(256), 0, stream>>>(qkv, ctx);
  gemm_bt<1><<<dim3(256), dim3(256), 0, stream>>>(ctx, outw, out, MROWS, DMODEL, DMODEL, 8);
}